// Round 5
// baseline (442.256 us; speedup 1.0000x reference)
//
#include <hip/hip_runtime.h>

// FullNN: per-atom MLP (FEAT=64 -> tanh(HID=64) -> 1) + segment-sum over 32768 structs.
// Round 5: round-4 showed ~560 VALU instrs per 16-atom tile (2x the useful work) and
// nothing saturated. Fixes: (1) hardware bf16 converts -- (__bf16) casts so the
// compiler emits v_cvt_pk_bf16_f32 (was a 4-op bit-twiddle per value); (2) 8-way
// split atomic accumulators in d_ws (copy = blockIdx&7, XCD-aligned) + tiny reduce
// kernel, cutting per-cache-line atomic contention 8x; (3) grid ~8 blocks/CU.
//
// Verified fragment layouts (learn_hip m89/m97):
//   A: row = lane&15,  k = (lane>>4)*8 + i   (8 contiguous k per lane)
//   B: col = lane&15,  k = (lane>>4)*8 + i
//   D: col = lane&15,  row = (lane>>4)*4 + reg

typedef __attribute__((ext_vector_type(8))) short bf16x8;
typedef __attribute__((ext_vector_type(4))) float f32x4;

struct ElemPtrs {
    const float* x;
    const int*   idx;
    const float* W1;
    const float* b1;
    const float* W2;
    const float* b2;
};
struct Params {
    ElemPtrs e[3];
    int n_tiles;    // atoms / 16
    int n_struct;   // 32768
    int ncopies;    // split-accumulator count (8, or 1 fallback)
};

__device__ __forceinline__ short f2bf(float f) {
    // Hardware RNE conversion; compiler pairs these into v_cvt_pk_bf16_f32.
    __bf16 h = (__bf16)f;
    return __builtin_bit_cast(short, h);
}

__device__ __forceinline__ float fast_tanh(float v) {
    // tanh(v) = (e^{2v}-1)/(e^{2v}+1); clamp keeps exp2 finite.
    v = fminf(10.0f, fmaxf(-10.0f, v));
    float t = __builtin_amdgcn_exp2f(v * 2.8853900817779268f); // 2^(2v*log2 e)
    return (t - 1.0f) * __builtin_amdgcn_rcpf(t + 1.0f);
}

__global__ __launch_bounds__(256, 6) void atom_mlp_mfma(Params p, float* __restrict__ part)
{
    const ElemPtrs ep = p.e[blockIdx.y];   // uniform index -> scalar code, no scratch

    const int lane = threadIdx.x & 63;
    const int col  = lane & 15;   // output col / atom-row selector
    const int kg   = lane >> 4;   // k-group 0..3

    const int wid    = (blockIdx.x * 256 + threadIdx.x) >> 6;  // wave id in element slice
    const int nwaves = (gridDim.x * 256) >> 6;

    // this block's accumulator copy (XCD-aligned: consecutive blocks -> different XCDs)
    float* __restrict__ acc_out = part + (size_t)(blockIdx.x & (p.ncopies - 1)) * p.n_struct;

    // ---- hoisted per-lane parameters ----
    float b1v[4], w2v[4];
    #pragma unroll
    for (int t = 0; t < 4; ++t) {
        b1v[t] = ep.b1[16 * t + col];
        w2v[t] = ep.W2[16 * t + col];
    }
    const float b2v = ep.b2[0];

    // ---- B fragments of W1 (bf16), Bf[k-step][n-tile] -- persistent, 32 VGPR ----
    bf16x8 Bf[2][4];
    #pragma unroll
    for (int s = 0; s < 2; ++s)
        #pragma unroll
        for (int t = 0; t < 4; ++t)
            #pragma unroll
            for (int i = 0; i < 8; ++i) {
                const int k = s * 32 + kg * 8 + i;
                Bf[s][t][i] = f2bf(ep.W1[k * 64 + 16 * t + col]);
            }

    int tile = wid;
    if (tile >= p.n_tiles) return;          // wave-uniform

    const size_t lane_off = (size_t)col * 64 + (size_t)kg * 8;

    // prefetch first tile
    const float* __restrict__ xr = ep.x + (size_t)tile * (16 * 64) + lane_off;
    float4 c0 = *reinterpret_cast<const float4*>(xr);
    float4 c1 = *reinterpret_cast<const float4*>(xr + 4);
    float4 c2 = *reinterpret_cast<const float4*>(xr + 32);
    float4 c3 = *reinterpret_cast<const float4*>(xr + 36);
    int4 cidx = {0, 0, 0, 0};
    if (col == 0) cidx = *reinterpret_cast<const int4*>(ep.idx + tile * 16 + kg * 4);

    while (true) {
        // ---- issue next tile's loads BEFORE computing current tile ----
        const int nxt = tile + nwaves;
        const bool have = (nxt < p.n_tiles);   // wave-uniform branch
        float4 n0, n1, n2, n3;
        int4 nidx;
        if (have) {
            const float* __restrict__ xn = ep.x + (size_t)nxt * (16 * 64) + lane_off;
            n0 = *reinterpret_cast<const float4*>(xn);
            n1 = *reinterpret_cast<const float4*>(xn + 4);
            n2 = *reinterpret_cast<const float4*>(xn + 32);
            n3 = *reinterpret_cast<const float4*>(xn + 36);
            if (col == 0) nidx = *reinterpret_cast<const int4*>(ep.idx + nxt * 16 + kg * 4);
        }

        // ---- convert current tile to bf16 A-fragments (hardware cvt_pk) ----
        bf16x8 A0, A1;
        A0[0] = f2bf(c0.x); A0[1] = f2bf(c0.y); A0[2] = f2bf(c0.z); A0[3] = f2bf(c0.w);
        A0[4] = f2bf(c1.x); A0[5] = f2bf(c1.y); A0[6] = f2bf(c1.z); A0[7] = f2bf(c1.w);
        A1[0] = f2bf(c2.x); A1[1] = f2bf(c2.y); A1[2] = f2bf(c2.z); A1[3] = f2bf(c2.w);
        A1[4] = f2bf(c3.x); A1[5] = f2bf(c3.y); A1[6] = f2bf(c3.z); A1[7] = f2bf(c3.w);

        f32x4 acc0 = {b1v[0], b1v[0], b1v[0], b1v[0]};
        f32x4 acc1 = {b1v[1], b1v[1], b1v[1], b1v[1]};
        f32x4 acc2 = {b1v[2], b1v[2], b1v[2], b1v[2]};
        f32x4 acc3 = {b1v[3], b1v[3], b1v[3], b1v[3]};
        acc0 = __builtin_amdgcn_mfma_f32_16x16x32_bf16(A0, Bf[0][0], acc0, 0, 0, 0);
        acc1 = __builtin_amdgcn_mfma_f32_16x16x32_bf16(A0, Bf[0][1], acc1, 0, 0, 0);
        acc2 = __builtin_amdgcn_mfma_f32_16x16x32_bf16(A0, Bf[0][2], acc2, 0, 0, 0);
        acc3 = __builtin_amdgcn_mfma_f32_16x16x32_bf16(A0, Bf[0][3], acc3, 0, 0, 0);
        acc0 = __builtin_amdgcn_mfma_f32_16x16x32_bf16(A1, Bf[1][0], acc0, 0, 0, 0);
        acc1 = __builtin_amdgcn_mfma_f32_16x16x32_bf16(A1, Bf[1][1], acc1, 0, 0, 0);
        acc2 = __builtin_amdgcn_mfma_f32_16x16x32_bf16(A1, Bf[1][2], acc2, 0, 0, 0);
        acc3 = __builtin_amdgcn_mfma_f32_16x16x32_bf16(A1, Bf[1][3], acc3, 0, 0, 0);

        // epilogue: e[r] = sum_j tanh(H[kg*4+r][j]) * W2[j]
        float e0 = fast_tanh(acc0[0]) * w2v[0] + fast_tanh(acc1[0]) * w2v[1]
                 + fast_tanh(acc2[0]) * w2v[2] + fast_tanh(acc3[0]) * w2v[3];
        float e1 = fast_tanh(acc0[1]) * w2v[0] + fast_tanh(acc1[1]) * w2v[1]
                 + fast_tanh(acc2[1]) * w2v[2] + fast_tanh(acc3[1]) * w2v[3];
        float e2 = fast_tanh(acc0[2]) * w2v[0] + fast_tanh(acc1[2]) * w2v[1]
                 + fast_tanh(acc2[2]) * w2v[2] + fast_tanh(acc3[2]) * w2v[3];
        float e3 = fast_tanh(acc0[3]) * w2v[0] + fast_tanh(acc1[3]) * w2v[1]
                 + fast_tanh(acc2[3]) * w2v[2] + fast_tanh(acc3[3]) * w2v[3];

        #pragma unroll
        for (int off = 1; off < 16; off <<= 1) {
            e0 += __shfl_xor(e0, off);
            e1 += __shfl_xor(e1, off);
            e2 += __shfl_xor(e2, off);
            e3 += __shfl_xor(e3, off);
        }

        if (col == 0) {
            atomicAdd(&acc_out[cidx.x], e0 + b2v);
            atomicAdd(&acc_out[cidx.y], e1 + b2v);
            atomicAdd(&acc_out[cidx.z], e2 + b2v);
            atomicAdd(&acc_out[cidx.w], e3 + b2v);
        }

        if (!have) break;                    // wave-uniform
        c0 = n0; c1 = n1; c2 = n2; c3 = n3; cidx = nidx;
        tile = nxt;
    }
}

__global__ __launch_bounds__(256) void reduce_copies(const float* __restrict__ part,
                                                     float* __restrict__ out,
                                                     int n_struct, int ncopies)
{
    const int i = blockIdx.x * 256 + threadIdx.x;
    if (i >= n_struct) return;
    float s = 0.0f;
    for (int c = 0; c < ncopies; ++c)
        s += part[(size_t)c * n_struct + i];
    out[i] = s;
}

extern "C" void kernel_launch(void* const* d_in, const int* in_sizes, int n_in,
                              void* d_out, int out_size, void* d_ws, size_t ws_size,
                              hipStream_t stream) {
    Params p;
    for (int e = 0; e < 3; ++e) {
        p.e[e].x   = (const float*)d_in[6 * e + 0];
        p.e[e].idx = (const int*)  d_in[6 * e + 1];
        p.e[e].W1  = (const float*)d_in[6 * e + 2];
        p.e[e].b1  = (const float*)d_in[6 * e + 3];
        p.e[e].W2  = (const float*)d_in[6 * e + 4];
        p.e[e].b2  = (const float*)d_in[6 * e + 5];
    }
    const int n_atoms = in_sizes[0] / 64;
    p.n_tiles  = n_atoms / 16;   // 1,000,000 / 16 = 62,500
    p.n_struct = out_size;       // 32768

    const size_t need = (size_t)8 * out_size * sizeof(float);
    float* out = (float*)d_out;

    if (ws_size >= need) {
        p.ncopies = 8;
        float* part = (float*)d_ws;
        hipMemsetAsync(part, 0, need, stream);
        dim3 grid(683, 3);   // ~8 blocks/CU
        atom_mlp_mfma<<<grid, 256, 0, stream>>>(p, part);
        reduce_copies<<<(out_size + 255) / 256, 256, 0, stream>>>(part, out, out_size, 8);
    } else {
        // fallback: accumulate directly into d_out
        p.ncopies = 1;
        hipMemsetAsync(out, 0, (size_t)out_size * sizeof(float), stream);
        dim3 grid(683, 3);
        atom_mlp_mfma<<<grid, 256, 0, stream>>>(p, out);
    }
}

// Round 6
// 197.565 us; speedup vs baseline: 2.2385x; 2.2385x over previous
//
#include <hip/hip_runtime.h>

// FullNN: per-atom MLP (FEAT=64 -> tanh(HID=64) -> 1) + segment-sum over 32768 structs.
// Round 6: round 5's regression was self-inflicted -- __launch_bounds__(256,6)
// capped VGPR below the live set and spilled (WRITE 208MB, FETCH 1.1GB, VALU 16%).
// Revert to (256,4); keep hardware cvt_pk bf16 converts, 8-way split accumulators
// (blockIdx&7 -> XCD-aligned copies in d_ws, tiny reduce), grid (683,3) ~8 blk/CU
// so occupancy is no longer grid-limited (round 4: 38%, grid-bound).
//
// Verified fragment layouts (learn_hip m89/m97):
//   A: row = lane&15,  k = (lane>>4)*8 + i   (8 contiguous k per lane)
//   B: col = lane&15,  k = (lane>>4)*8 + i
//   D: col = lane&15,  row = (lane>>4)*4 + reg

typedef __attribute__((ext_vector_type(8))) short bf16x8;
typedef __attribute__((ext_vector_type(4))) float f32x4;

struct ElemPtrs {
    const float* x;
    const int*   idx;
    const float* W1;
    const float* b1;
    const float* W2;
    const float* b2;
};
struct Params {
    ElemPtrs e[3];
    int n_tiles;    // atoms / 16
    int n_struct;   // 32768
    int ncopies;    // split-accumulator count (8, or 1 fallback)
};

__device__ __forceinline__ short f2bf(float f) {
    // Hardware RNE conversion; compiler pairs these into v_cvt_pk_bf16_f32.
    __bf16 h = (__bf16)f;
    return __builtin_bit_cast(short, h);
}

__device__ __forceinline__ float fast_tanh(float v) {
    // tanh(v) = (e^{2v}-1)/(e^{2v}+1); clamp keeps exp2 finite.
    v = fminf(10.0f, fmaxf(-10.0f, v));
    float t = __builtin_amdgcn_exp2f(v * 2.8853900817779268f); // 2^(2v*log2 e)
    return (t - 1.0f) * __builtin_amdgcn_rcpf(t + 1.0f);
}

__global__ __launch_bounds__(256, 4) void atom_mlp_mfma(Params p, float* __restrict__ part)
{
    const ElemPtrs ep = p.e[blockIdx.y];   // uniform index -> scalar code, no scratch

    const int lane = threadIdx.x & 63;
    const int col  = lane & 15;   // output col / atom-row selector
    const int kg   = lane >> 4;   // k-group 0..3

    const int wid    = (blockIdx.x * 256 + threadIdx.x) >> 6;  // wave id in element slice
    const int nwaves = (gridDim.x * 256) >> 6;

    // this block's accumulator copy (XCD-aligned: consecutive blocks -> different XCDs)
    float* __restrict__ acc_out = part + (size_t)(blockIdx.x & (p.ncopies - 1)) * p.n_struct;

    // ---- hoisted per-lane parameters ----
    float b1v[4], w2v[4];
    #pragma unroll
    for (int t = 0; t < 4; ++t) {
        b1v[t] = ep.b1[16 * t + col];
        w2v[t] = ep.W2[16 * t + col];
    }
    const float b2v = ep.b2[0];

    // ---- B fragments of W1 (bf16), Bf[k-step][n-tile] -- persistent, 32 VGPR ----
    bf16x8 Bf[2][4];
    #pragma unroll
    for (int s = 0; s < 2; ++s)
        #pragma unroll
        for (int t = 0; t < 4; ++t)
            #pragma unroll
            for (int i = 0; i < 8; ++i) {
                const int k = s * 32 + kg * 8 + i;
                Bf[s][t][i] = f2bf(ep.W1[k * 64 + 16 * t + col]);
            }

    int tile = wid;
    if (tile >= p.n_tiles) return;          // wave-uniform

    const size_t lane_off = (size_t)col * 64 + (size_t)kg * 8;

    // prefetch first tile
    const float* __restrict__ xr = ep.x + (size_t)tile * (16 * 64) + lane_off;
    float4 c0 = *reinterpret_cast<const float4*>(xr);
    float4 c1 = *reinterpret_cast<const float4*>(xr + 4);
    float4 c2 = *reinterpret_cast<const float4*>(xr + 32);
    float4 c3 = *reinterpret_cast<const float4*>(xr + 36);
    int4 cidx = {0, 0, 0, 0};
    if (col == 0) cidx = *reinterpret_cast<const int4*>(ep.idx + tile * 16 + kg * 4);

    while (true) {
        // ---- issue next tile's loads BEFORE computing current tile ----
        const int nxt = tile + nwaves;
        const bool have = (nxt < p.n_tiles);   // wave-uniform branch
        float4 n0, n1, n2, n3;
        int4 nidx;
        if (have) {
            const float* __restrict__ xn = ep.x + (size_t)nxt * (16 * 64) + lane_off;
            n0 = *reinterpret_cast<const float4*>(xn);
            n1 = *reinterpret_cast<const float4*>(xn + 4);
            n2 = *reinterpret_cast<const float4*>(xn + 32);
            n3 = *reinterpret_cast<const float4*>(xn + 36);
            if (col == 0) nidx = *reinterpret_cast<const int4*>(ep.idx + nxt * 16 + kg * 4);
        }

        // ---- convert current tile to bf16 A-fragments (hardware cvt_pk) ----
        bf16x8 A0, A1;
        A0[0] = f2bf(c0.x); A0[1] = f2bf(c0.y); A0[2] = f2bf(c0.z); A0[3] = f2bf(c0.w);
        A0[4] = f2bf(c1.x); A0[5] = f2bf(c1.y); A0[6] = f2bf(c1.z); A0[7] = f2bf(c1.w);
        A1[0] = f2bf(c2.x); A1[1] = f2bf(c2.y); A1[2] = f2bf(c2.z); A1[3] = f2bf(c2.w);
        A1[4] = f2bf(c3.x); A1[5] = f2bf(c3.y); A1[6] = f2bf(c3.z); A1[7] = f2bf(c3.w);

        f32x4 acc0 = {b1v[0], b1v[0], b1v[0], b1v[0]};
        f32x4 acc1 = {b1v[1], b1v[1], b1v[1], b1v[1]};
        f32x4 acc2 = {b1v[2], b1v[2], b1v[2], b1v[2]};
        f32x4 acc3 = {b1v[3], b1v[3], b1v[3], b1v[3]};
        acc0 = __builtin_amdgcn_mfma_f32_16x16x32_bf16(A0, Bf[0][0], acc0, 0, 0, 0);
        acc1 = __builtin_amdgcn_mfma_f32_16x16x32_bf16(A0, Bf[0][1], acc1, 0, 0, 0);
        acc2 = __builtin_amdgcn_mfma_f32_16x16x32_bf16(A0, Bf[0][2], acc2, 0, 0, 0);
        acc3 = __builtin_amdgcn_mfma_f32_16x16x32_bf16(A0, Bf[0][3], acc3, 0, 0, 0);
        acc0 = __builtin_amdgcn_mfma_f32_16x16x32_bf16(A1, Bf[1][0], acc0, 0, 0, 0);
        acc1 = __builtin_amdgcn_mfma_f32_16x16x32_bf16(A1, Bf[1][1], acc1, 0, 0, 0);
        acc2 = __builtin_amdgcn_mfma_f32_16x16x32_bf16(A1, Bf[1][2], acc2, 0, 0, 0);
        acc3 = __builtin_amdgcn_mfma_f32_16x16x32_bf16(A1, Bf[1][3], acc3, 0, 0, 0);

        // epilogue: e[r] = sum_j tanh(H[kg*4+r][j]) * W2[j]
        float e0 = fast_tanh(acc0[0]) * w2v[0] + fast_tanh(acc1[0]) * w2v[1]
                 + fast_tanh(acc2[0]) * w2v[2] + fast_tanh(acc3[0]) * w2v[3];
        float e1 = fast_tanh(acc0[1]) * w2v[0] + fast_tanh(acc1[1]) * w2v[1]
                 + fast_tanh(acc2[1]) * w2v[2] + fast_tanh(acc3[1]) * w2v[3];
        float e2 = fast_tanh(acc0[2]) * w2v[0] + fast_tanh(acc1[2]) * w2v[1]
                 + fast_tanh(acc2[2]) * w2v[2] + fast_tanh(acc3[2]) * w2v[3];
        float e3 = fast_tanh(acc0[3]) * w2v[0] + fast_tanh(acc1[3]) * w2v[1]
                 + fast_tanh(acc2[3]) * w2v[2] + fast_tanh(acc3[3]) * w2v[3];

        #pragma unroll
        for (int off = 1; off < 16; off <<= 1) {
            e0 += __shfl_xor(e0, off);
            e1 += __shfl_xor(e1, off);
            e2 += __shfl_xor(e2, off);
            e3 += __shfl_xor(e3, off);
        }

        if (col == 0) {
            atomicAdd(&acc_out[cidx.x], e0 + b2v);
            atomicAdd(&acc_out[cidx.y], e1 + b2v);
            atomicAdd(&acc_out[cidx.z], e2 + b2v);
            atomicAdd(&acc_out[cidx.w], e3 + b2v);
        }

        if (!have) break;                    // wave-uniform
        c0 = n0; c1 = n1; c2 = n2; c3 = n3; cidx = nidx;
        tile = nxt;
    }
}

__global__ __launch_bounds__(256) void reduce_copies(const float* __restrict__ part,
                                                     float* __restrict__ out,
                                                     int n_struct, int ncopies)
{
    const int i = blockIdx.x * 256 + threadIdx.x;
    if (i >= n_struct) return;
    float s = 0.0f;
    for (int c = 0; c < ncopies; ++c)
        s += part[(size_t)c * n_struct + i];
    out[i] = s;
}

extern "C" void kernel_launch(void* const* d_in, const int* in_sizes, int n_in,
                              void* d_out, int out_size, void* d_ws, size_t ws_size,
                              hipStream_t stream) {
    Params p;
    for (int e = 0; e < 3; ++e) {
        p.e[e].x   = (const float*)d_in[6 * e + 0];
        p.e[e].idx = (const int*)  d_in[6 * e + 1];
        p.e[e].W1  = (const float*)d_in[6 * e + 2];
        p.e[e].b1  = (const float*)d_in[6 * e + 3];
        p.e[e].W2  = (const float*)d_in[6 * e + 4];
        p.e[e].b2  = (const float*)d_in[6 * e + 5];
    }
    const int n_atoms = in_sizes[0] / 64;
    p.n_tiles  = n_atoms / 16;   // 1,000,000 / 16 = 62,500
    p.n_struct = out_size;       // 32768

    const size_t need = (size_t)8 * out_size * sizeof(float);
    float* out = (float*)d_out;

    if (ws_size >= need) {
        p.ncopies = 8;
        float* part = (float*)d_ws;
        hipMemsetAsync(part, 0, need, stream);
        dim3 grid(683, 3);   // ~8 blocks/CU -- occupancy no longer grid-limited
        atom_mlp_mfma<<<grid, 256, 0, stream>>>(p, part);
        reduce_copies<<<(out_size + 255) / 256, 256, 0, stream>>>(part, out, out_size, 8);
    } else {
        // fallback: accumulate directly into d_out
        p.ncopies = 1;
        hipMemsetAsync(out, 0, (size_t)out_size * sizeof(float), stream);
        dim3 grid(683, 3);
        atom_mlp_mfma<<<grid, 256, 0, stream>>>(p, out);
    }
}

// Round 7
// 192.583 us; speedup vs baseline: 2.2964x; 1.0259x over previous
//
#include <hip/hip_runtime.h>

// FullNN: per-atom MLP (FEAT=64 -> tanh(HID=64) -> 1) + segment-sum over 32768 structs.
// Round 7: rounds 3-6 plateaued at ~220us with ~490 VALU instr per 16-atom tile
// (vs ~150 useful): shfl-reduce chain (16 ds_bpermute, 4-deep), ping-pong copies,
// divergent idx/atomic regions. Fix: SWAPPED GEMM -- compute H^T = W1^T @ x^T.
// Fragments are bit-identical to before (W1 frag: B->A, x frag: A->B), but the
// D-layout flips so each lane holds 16 hidden values of ONE atom: the W2 reduction
// is in-lane, cross-lane reduce is 2 shfls (over kg), b1 rides in as MFMA C.
// Also: unroll-by-2 ping-pong (no reg copies), bf16 convert at load time (half the
// x-frag registers), pointer increments, uniform idx loads.
//
// Layouts (learn_hip m89/m97), mfma_f32_16x16x32_bf16:
//   A: row = lane&15, k = (lane>>4)*8+i     -> W1^T tile: W1[(32s+kg*8+i)*64 + 16t+col]
//   B: col = lane&15, k = (lane>>4)*8+i     -> x^T tile:  x[a0+col][32s+kg*8+i]
//   D: col = lane&15, row = (lane>>4)*4+r   -> H[a0+col][16t+kg*4+r]  (atom = col!)

typedef __attribute__((ext_vector_type(8))) short bf16x8;
typedef __attribute__((ext_vector_type(4))) float f32x4;

struct ElemPtrs {
    const float* x;
    const int*   idx;
    const float* W1;
    const float* b1;
    const float* W2;
    const float* b2;
};
struct Params {
    ElemPtrs e[3];
    int n_tiles;    // atoms / 16
    int n_struct;   // 32768
    int ncopies;    // split-accumulator count
};

__device__ __forceinline__ short f2bf(float f) {
    __bf16 h = (__bf16)f;           // hardware RNE; pairs into v_cvt_pk_bf16_f32
    return __builtin_bit_cast(short, h);
}

__device__ __forceinline__ float fast_tanh(float v) {
    // tanh(v) = (e^{2v}-1)/(e^{2v}+1); med3 clamp keeps exp2 finite (|h|<~6 in data).
    v = __builtin_amdgcn_fmed3f(v, -10.0f, 10.0f);
    float t = __builtin_amdgcn_exp2f(v * 2.8853900817779268f); // 2^(2v*log2 e)
    return (t - 1.0f) * __builtin_amdgcn_rcpf(t + 1.0f);
}

__global__ __launch_bounds__(256, 4) void atom_mlp_mfma(Params p, float* __restrict__ part)
{
    const ElemPtrs ep = p.e[blockIdx.y];   // uniform index -> scalar code

    const int lane = threadIdx.x & 63;
    const int col  = lane & 15;   // atom within tile (and W1^T row)
    const int kg   = lane >> 4;   // k-group / D-row group

    const int wid    = (blockIdx.x * 256 + threadIdx.x) >> 6;
    const int nwaves = (gridDim.x * 256) >> 6;

    float* __restrict__ acc_out = part + (size_t)(blockIdx.x & (p.ncopies - 1)) * p.n_struct;

    // per-lane b1 (MFMA C-operand) and W2, j = 16t + kg*4 + r
    f32x4 b1c[4], w2c[4];
    #pragma unroll
    for (int t = 0; t < 4; ++t)
        #pragma unroll
        for (int r = 0; r < 4; ++r) {
            b1c[t][r] = ep.b1[16 * t + kg * 4 + r];
            w2c[t][r] = ep.W2[16 * t + kg * 4 + r];
        }
    const float b2v = ep.b2[0];

    // persistent W1^T fragments (A operand), 32 VGPR
    bf16x8 Wf[2][4];
    #pragma unroll
    for (int s = 0; s < 2; ++s)
        #pragma unroll
        for (int t = 0; t < 4; ++t)
            #pragma unroll
            for (int i = 0; i < 8; ++i)
                Wf[s][t][i] = f2bf(ep.W1[(s * 32 + kg * 8 + i) * 64 + 16 * t + col]);

    int tile = wid;
    if (tile >= p.n_tiles) return;          // wave-uniform

    const size_t xoff    = (size_t)col * 64 + (size_t)kg * 8;
    const size_t xstride = (size_t)nwaves * 1024;   // floats per tile-step
    const int    istride = nwaves * 16;

    const float* xpA = ep.x + (size_t)tile * 1024 + xoff;
    const int*   ipA = ep.idx + tile * 16 + col;

    // ---- load+convert helper: 4 x float4 -> two bf16x8 B-fragments + idx ----
#define LOADCVT(X0, X1, IDX, XP, IP)                                            \
    {                                                                           \
        const float4 l0 = *reinterpret_cast<const float4*>((XP));               \
        const float4 l1 = *reinterpret_cast<const float4*>((XP) + 4);           \
        const float4 l2 = *reinterpret_cast<const float4*>((XP) + 32);          \
        const float4 l3 = *reinterpret_cast<const float4*>((XP) + 36);          \
        (IDX) = *(IP);                                                          \
        X0[0]=f2bf(l0.x); X0[1]=f2bf(l0.y); X0[2]=f2bf(l0.z); X0[3]=f2bf(l0.w); \
        X0[4]=f2bf(l1.x); X0[5]=f2bf(l1.y); X0[6]=f2bf(l1.z); X0[7]=f2bf(l1.w); \
        X1[0]=f2bf(l2.x); X1[1]=f2bf(l2.y); X1[2]=f2bf(l2.z); X1[3]=f2bf(l2.w); \
        X1[4]=f2bf(l3.x); X1[5]=f2bf(l3.y); X1[6]=f2bf(l3.z); X1[7]=f2bf(l3.w); \
    }

    // ---- compute helper: 8 MFMA + in-lane W2 reduce + 2 shfl + 1 atomic ----
#define COMPUTE(X0, X1, IDX)                                                    \
    {                                                                           \
        f32x4 a0 = __builtin_amdgcn_mfma_f32_16x16x32_bf16(Wf[0][0], X0, b1c[0], 0, 0, 0); \
        f32x4 a1 = __builtin_amdgcn_mfma_f32_16x16x32_bf16(Wf[0][1], X0, b1c[1], 0, 0, 0); \
        f32x4 a2 = __builtin_amdgcn_mfma_f32_16x16x32_bf16(Wf[0][2], X0, b1c[2], 0, 0, 0); \
        f32x4 a3 = __builtin_amdgcn_mfma_f32_16x16x32_bf16(Wf[0][3], X0, b1c[3], 0, 0, 0); \
        a0 = __builtin_amdgcn_mfma_f32_16x16x32_bf16(Wf[1][0], X1, a0, 0, 0, 0); \
        a1 = __builtin_amdgcn_mfma_f32_16x16x32_bf16(Wf[1][1], X1, a1, 0, 0, 0); \
        a2 = __builtin_amdgcn_mfma_f32_16x16x32_bf16(Wf[1][2], X1, a2, 0, 0, 0); \
        a3 = __builtin_amdgcn_mfma_f32_16x16x32_bf16(Wf[1][3], X1, a3, 0, 0, 0); \
        float e;                                                                \
        e  = fast_tanh(a0[0]) * w2c[0][0];                                      \
        e += fast_tanh(a0[1]) * w2c[0][1];                                      \
        e += fast_tanh(a0[2]) * w2c[0][2];                                      \
        e += fast_tanh(a0[3]) * w2c[0][3];                                      \
        e += fast_tanh(a1[0]) * w2c[1][0];                                      \
        e += fast_tanh(a1[1]) * w2c[1][1];                                      \
        e += fast_tanh(a1[2]) * w2c[1][2];                                      \
        e += fast_tanh(a1[3]) * w2c[1][3];                                      \
        e += fast_tanh(a2[0]) * w2c[2][0];                                      \
        e += fast_tanh(a2[1]) * w2c[2][1];                                      \
        e += fast_tanh(a2[2]) * w2c[2][2];                                      \
        e += fast_tanh(a2[3]) * w2c[2][3];                                      \
        e += fast_tanh(a3[0]) * w2c[3][0];                                      \
        e += fast_tanh(a3[1]) * w2c[3][1];                                      \
        e += fast_tanh(a3[2]) * w2c[3][2];                                      \
        e += fast_tanh(a3[3]) * w2c[3][3];                                      \
        e += __shfl_xor(e, 16);                                                 \
        e += __shfl_xor(e, 32);                                                 \
        if (lane < 16) atomicAdd(&acc_out[IDX], e + b2v);                       \
    }

    bf16x8 Xa0, Xa1, Xb0, Xb1;
    int idxA, idxB;

    LOADCVT(Xa0, Xa1, idxA, xpA, ipA);

    while (true) {
        const int nxt = tile + nwaves;
        const bool have = (nxt < p.n_tiles);          // wave-uniform
        const float* xpB = xpA + xstride;
        const int*   ipB = ipA + istride;
        if (have) LOADCVT(Xb0, Xb1, idxB, xpB, ipB);

        COMPUTE(Xa0, Xa1, idxA);
        if (!have) break;

        const int nxt2 = nxt + nwaves;
        const bool have2 = (nxt2 < p.n_tiles);        // wave-uniform
        xpA = xpB + xstride;
        ipA = ipB + istride;
        if (have2) LOADCVT(Xa0, Xa1, idxA, xpA, ipA);

        COMPUTE(Xb0, Xb1, idxB);
        if (!have2) break;
        tile = nxt2;
    }
#undef LOADCVT
#undef COMPUTE
}

__global__ __launch_bounds__(256) void reduce_copies(const float* __restrict__ part,
                                                     float* __restrict__ out,
                                                     int n_struct, int ncopies)
{
    const int i = blockIdx.x * 256 + threadIdx.x;
    if (i >= n_struct) return;
    float s = 0.0f;
    for (int c = 0; c < ncopies; ++c)
        s += part[(size_t)c * n_struct + i];
    out[i] = s;
}

extern "C" void kernel_launch(void* const* d_in, const int* in_sizes, int n_in,
                              void* d_out, int out_size, void* d_ws, size_t ws_size,
                              hipStream_t stream) {
    Params p;
    for (int e = 0; e < 3; ++e) {
        p.e[e].x   = (const float*)d_in[6 * e + 0];
        p.e[e].idx = (const int*)  d_in[6 * e + 1];
        p.e[e].W1  = (const float*)d_in[6 * e + 2];
        p.e[e].b1  = (const float*)d_in[6 * e + 3];
        p.e[e].W2  = (const float*)d_in[6 * e + 4];
        p.e[e].b2  = (const float*)d_in[6 * e + 5];
    }
    const int n_atoms = in_sizes[0] / 64;
    p.n_tiles  = n_atoms / 16;   // 62,500
    p.n_struct = out_size;       // 32768

    const size_t need = (size_t)8 * out_size * sizeof(float);
    float* out = (float*)d_out;

    if (ws_size >= need) {
        p.ncopies = 8;
        float* part = (float*)d_ws;
        hipMemsetAsync(part, 0, need, stream);
        dim3 grid(683, 3);
        atom_mlp_mfma<<<grid, 256, 0, stream>>>(p, part);
        reduce_copies<<<(out_size + 255) / 256, 256, 0, stream>>>(part, out, out_size, 8);
    } else {
        p.ncopies = 1;
        hipMemsetAsync(out, 0, (size_t)out_size * sizeof(float), stream);
        dim3 grid(683, 3);
        atom_mlp_mfma<<<grid, 256, 0, stream>>>(p, out);
    }
}